// Round 2
// baseline (3718.800 us; speedup 1.0000x reference)
//
#include <hip/hip_runtime.h>
#include <hip/hip_bf16.h>
#include <cmath>

typedef unsigned short u16;
typedef __attribute__((ext_vector_type(8))) short short8;
typedef __attribute__((ext_vector_type(4))) float f32x4;

#define DM 1024
#define NH 16
#define DH 64
#define DFF 4096
#define BB 4
#define TT 2048
#define MROWS (BB*TT)

__device__ __forceinline__ float bu2f(u16 u) {
    union { float f; unsigned v; } c; c.v = ((unsigned)u) << 16; return c.f;
}
__device__ __forceinline__ u16 f2bu(float f) {
    __hip_bfloat16 h = __float2bfloat16(f);
    union { __hip_bfloat16 h; u16 u; } c; c.h = h; return c.u;
}

// ---------------- LayerNorm: fp32 in -> bf16 out. One block (256 thr) per row ----------------
__global__ void ln_kernel(const float* __restrict__ x, const float* __restrict__ gamma,
                          const float* __restrict__ beta, u16* __restrict__ out)
{
    int row = blockIdx.x;
    int tid = threadIdx.x;
    float4 v4 = ((const float4*)(x + (size_t)row * DM))[tid];
    float v[4] = { v4.x, v4.y, v4.z, v4.w };
    float s = v[0] + v[1] + v[2] + v[3];
    float ss = v[0]*v[0] + v[1]*v[1] + v[2]*v[2] + v[3]*v[3];
    #pragma unroll
    for (int o = 32; o > 0; o >>= 1) { s += __shfl_down(s, o); ss += __shfl_down(ss, o); }
    __shared__ float red[8];
    int w = tid >> 6;
    if ((tid & 63) == 0) { red[w] = s; red[4 + w] = ss; }
    __syncthreads();
    s  = red[0] + red[1] + red[2] + red[3];
    ss = red[4] + red[5] + red[6] + red[7];
    float mu  = s * (1.0f / DM);
    float var = ss * (1.0f / DM) - mu * mu;
    float rstd = rsqrtf(var + 1e-5f);
    float4 g4 = ((const float4*)gamma)[tid];
    float4 b4 = ((const float4*)beta)[tid];
    float g[4] = { g4.x, g4.y, g4.z, g4.w };
    float b[4] = { b4.x, b4.y, b4.z, b4.w };
    ushort4 o4;
    u16* op = (u16*)&o4;
    #pragma unroll
    for (int i = 0; i < 4; i++) op[i] = f2bu((v[i] - mu) * rstd * g[i] + b[i]);
    ((ushort4*)(out + (size_t)row * DM))[tid] = o4;
}

// ---------------- Transpose + fp32->bf16: in[R][C] fp32 -> out[C][R] bf16 ----------------
__global__ void transpose_f2b(const float* __restrict__ in, u16* __restrict__ out,
                              int R, int C)
{
    __shared__ u16 tile[32][33];
    int bx = blockIdx.x * 32;  // col base in 'in'
    int by = blockIdx.y * 32;  // row base in 'in'
    int tx = threadIdx.x, ty = threadIdx.y;  // 32 x 8
    #pragma unroll
    for (int i = 0; i < 32; i += 8)
        tile[ty + i][tx] = f2bu(in[(size_t)(by + ty + i) * C + bx + tx]);
    __syncthreads();
    #pragma unroll
    for (int i = 0; i < 32; i += 8)
        out[(size_t)(bx + ty + i) * R + by + tx] = tile[tx][ty + i];
}

// ---------------- GEMM: C[M][N] = A[M][K](bf16) * Bt[N][K](bf16)^T + bias(f32) ----------------
// EPI 0: bias only                      -> bf16 out (Q,K,V)
// EPI 1: bias + res(f32)                -> f32 out (x1 = x + attn_out)
// EPI 2: bias + exact GeLU              -> bf16 out (ff)
// EPI 3: out = x0 + g*(res + v - x0)    -> f32 out (final gate; v includes bias)
#define BM 128
#define BN 128
#define BK 32
#define SA 48   // padded LDS row stride in elements (96B: 16B-aligned, bank-spread)

template<int EPI>
__global__ __launch_bounds__(256, 2) void gemm_bt(
    const u16* __restrict__ A, const u16* __restrict__ Bt,
    const float* __restrict__ bias, void* __restrict__ Cv,
    const float* __restrict__ res, const float* __restrict__ x0,
    const float* __restrict__ gate, int M, int N, int K)
{
    __shared__ u16 As[BM * SA];
    __shared__ u16 Bs[BN * SA];
    int tid = threadIdx.x;
    int lane = tid & 63, wave = tid >> 6;
    int wm = (wave & 1) * 64, wn = (wave >> 1) * 64;
    int lm = lane & 15, quad = lane >> 4;
    size_t row0 = (size_t)blockIdx.x * BM;
    size_t col0 = (size_t)blockIdx.y * BN;

    int sr = tid >> 2;          // 0..63
    int sk = (tid & 3) * 8;     // 0,8,16,24
    const u16* Ag = A  + (row0 + sr) * (size_t)K + sk;
    const u16* Bg = Bt + (col0 + sr) * (size_t)K + sk;

    f32x4 acc[4][4];
    #pragma unroll
    for (int i = 0; i < 4; i++)
        #pragma unroll
        for (int j = 0; j < 4; j++)
            acc[i][j] = (f32x4){0.f, 0.f, 0.f, 0.f};

    for (int k0 = 0; k0 < K; k0 += BK) {
        uint4 a0 = *(const uint4*)(Ag + k0);
        uint4 a1 = *(const uint4*)(Ag + (size_t)64 * K + k0);
        uint4 b0 = *(const uint4*)(Bg + k0);
        uint4 b1 = *(const uint4*)(Bg + (size_t)64 * K + k0);
        __syncthreads();   // previous iteration's LDS reads complete
        *(uint4*)&As[sr * SA + sk]        = a0;
        *(uint4*)&As[(sr + 64) * SA + sk] = a1;
        *(uint4*)&Bs[sr * SA + sk]        = b0;
        *(uint4*)&Bs[(sr + 64) * SA + sk] = b1;
        __syncthreads();
        short8 af[4], bfr[4];
        #pragma unroll
        for (int t = 0; t < 4; t++) {
            af[t]  = *(const short8*)&As[(wm + t * 16 + lm) * SA + quad * 8];
            bfr[t] = *(const short8*)&Bs[(wn + t * 16 + lm) * SA + quad * 8];
        }
        #pragma unroll
        for (int mt = 0; mt < 4; mt++)
            #pragma unroll
            for (int nt = 0; nt < 4; nt++)
                acc[mt][nt] = __builtin_amdgcn_mfma_f32_16x16x32_bf16(
                    af[mt], bfr[nt], acc[mt][nt], 0, 0, 0);
    }

    u16*   C16 = (u16*)Cv;
    float* Cf  = (float*)Cv;

    // epilogue: C/D layout col=lane&15, row=(lane>>4)*4+reg  (m89-verified)
    #pragma unroll
    for (int mt = 0; mt < 4; mt++) {
        #pragma unroll
        for (int nt = 0; nt < 4; nt++) {
            #pragma unroll
            for (int r = 0; r < 4; r++) {
                size_t row = row0 + wm + mt * 16 + quad * 4 + r;
                size_t col = col0 + wn + nt * 16 + lm;
                size_t idx = row * (size_t)N + col;
                float v = acc[mt][nt][r] + bias[col];
                if (EPI == 0) {
                    C16[idx] = f2bu(v);
                } else if (EPI == 1) {
                    Cf[idx] = v + res[idx];
                } else if (EPI == 2) {
                    v = 0.5f * v * (1.0f + erff(v * 0.70710678118f));
                    C16[idx] = f2bu(v);
                } else {  // EPI == 3
                    float xv  = x0[idx];
                    float x1v = res[idx];
                    float g   = gate[row >> 11];   // row / T
                    Cf[idx] = xv + g * (x1v + v - xv);
                }
            }
        }
    }
}

// ---------------- Attention: 1 block = (b, h, 4 query rows); flash-style; bf16 in/out ----------------
__global__ __launch_bounds__(256, 2) void attn_kernel(
    const u16* __restrict__ Q, const u16* __restrict__ Kg,
    const u16* __restrict__ Vg, u16* __restrict__ ctx)
{
    __shared__ float Kl[64][68];   // pad 68: 16B-aligned rows, bank-spread
    __shared__ float Vl[64][68];
    __shared__ float ql[4][64];

    int tid = threadIdx.x, lane = tid & 63, w = tid >> 6;
    int idx = blockIdx.x;
    int qt = idx & (TT / 4 - 1);          // & 511
    int h  = (idx >> 9) & (NH - 1);
    int b  = idx >> 13;
    int q0 = qt * 4;

    {
        int r = tid >> 6, d = tid & 63;
        ql[r][d] = bu2f(Q[(size_t)(b * TT + q0 + r) * DM + h * DH + d]) * 0.125f;
    }
    __syncthreads();

    float m = -INFINITY, l = 0.f, o = 0.f;
    int q = q0 + w;
    int nch = q0 / 64 + 1;

    for (int c = 0; c < nch; c++) {
        int kb = c * 64;
        int r  = tid >> 2;            // 0..63
        int cs = (tid & 3) * 16;      // 0,16,32,48
        const u16* kp = Kg + (size_t)(b * TT + kb + r) * DM + h * DH + cs;
        const u16* vp = Vg + (size_t)(b * TT + kb + r) * DM + h * DH + cs;
        uint4 k0 = *(const uint4*)kp;       uint4 k1 = *(const uint4*)(kp + 8);
        uint4 v0 = *(const uint4*)vp;       uint4 v1 = *(const uint4*)(vp + 8);
        __syncthreads();   // previous iteration's LDS reads done before overwrite
        const u16* kk0 = (const u16*)&k0; const u16* kk1 = (const u16*)&k1;
        const u16* vv0 = (const u16*)&v0; const u16* vv1 = (const u16*)&v1;
        #pragma unroll
        for (int i = 0; i < 8; i++) {
            Kl[r][cs + i]     = bu2f(kk0[i]);
            Kl[r][cs + 8 + i] = bu2f(kk1[i]);
            Vl[r][cs + i]     = bu2f(vv0[i]);
            Vl[r][cs + 8 + i] = bu2f(vv1[i]);
        }
        __syncthreads();

        float s = 0.f;
        #pragma unroll
        for (int d4 = 0; d4 < 16; d4++) {
            f32x4 kv = *(const f32x4*)&Kl[lane][d4 * 4];
            f32x4 qv = *(const f32x4*)&ql[w][d4 * 4];
            s += kv.x * qv.x + kv.y * qv.y + kv.z * qv.z + kv.w * qv.w;
        }
        int key = kb + lane;
        if (key > q) s = -INFINITY;

        float cm = s;
        #pragma unroll
        for (int off = 32; off > 0; off >>= 1) cm = fmaxf(cm, __shfl_xor(cm, off));
        float mn = fmaxf(m, cm);
        float alpha = __expf(m - mn);
        float p = __expf(s - mn);
        float ps = p;
        #pragma unroll
        for (int off = 32; off > 0; off >>= 1) ps += __shfl_xor(ps, off);
        l = l * alpha + ps;
        o *= alpha;
        m = mn;
        #pragma unroll
        for (int j = 0; j < 64; j++) {
            float pj = __shfl(p, j);
            o += pj * Vl[j][lane];
        }
    }
    ctx[(size_t)(b * TT + q) * DM + h * DH + lane] = f2bu(o / l);
}

extern "C" void kernel_launch(void* const* d_in, const int* in_sizes, int n_in,
                              void* d_out, int out_size, void* d_ws, size_t ws_size,
                              hipStream_t stream)
{
    const float* x    = (const float*)d_in[0];
    const float* gate = (const float*)d_in[1];
    const float* Wq   = (const float*)d_in[2];
    const float* bq   = (const float*)d_in[3];
    const float* Wk   = (const float*)d_in[4];
    const float* bk   = (const float*)d_in[5];
    const float* Wv   = (const float*)d_in[6];
    const float* bv   = (const float*)d_in[7];
    const float* Wo   = (const float*)d_in[8];
    const float* bo   = (const float*)d_in[9];
    const float* W1   = (const float*)d_in[10];
    const float* b1   = (const float*)d_in[11];
    const float* W2   = (const float*)d_in[12];
    const float* b2   = (const float*)d_in[13];
    const float* gamma1 = (const float*)d_in[14];
    const float* beta1  = (const float*)d_in[15];
    const float* gamma2 = (const float*)d_in[16];
    const float* beta2  = (const float*)d_in[17];
    float* out = (float*)d_out;

    // workspace layout (byte offsets), total 152 MB
    char* ws = (char*)d_ws;
    const size_t MB = 1024 * 1024;
    u16* WtQ = (u16*)(ws + 0 * MB);     // [1024][1024] bf16
    u16* WtK = (u16*)(ws + 2 * MB);
    u16* WtV = (u16*)(ws + 4 * MB);
    u16* WtO = (u16*)(ws + 6 * MB);
    u16* Wt1 = (u16*)(ws + 8 * MB);     // [4096][1024] bf16
    u16* Wt2 = (u16*)(ws + 16 * MB);    // [1024][4096] bf16
    u16* h   = (u16*)(ws + 24 * MB);    // [8192][1024] bf16 (ln1 out; dead after V-gemm)
    u16* ctx = (u16*)(ws + 24 * MB);    // reuse h (attn out; dead after gemm<1>)
    u16* Qb  = (u16*)(ws + 40 * MB);
    u16* Kb  = (u16*)(ws + 56 * MB);
    u16* Vb  = (u16*)(ws + 72 * MB);
    float* x1 = (float*)(ws + 40 * MB); // [8192][1024] f32, reuses Qb+Kb (dead after attn)
    u16* h2  = (u16*)(ws + 72 * MB);    // reuse Vb (ln2 out)
    u16* ff  = (u16*)(ws + 88 * MB);    // [8192][4096] bf16, 64 MB -> ends at 152 MB

    dim3 tb(32, 8);
    transpose_f2b<<<dim3(DM / 32, DM / 32), tb, 0, stream>>>(Wq, WtQ, DM, DM);
    transpose_f2b<<<dim3(DM / 32, DM / 32), tb, 0, stream>>>(Wk, WtK, DM, DM);
    transpose_f2b<<<dim3(DM / 32, DM / 32), tb, 0, stream>>>(Wv, WtV, DM, DM);
    transpose_f2b<<<dim3(DM / 32, DM / 32), tb, 0, stream>>>(Wo, WtO, DM, DM);
    transpose_f2b<<<dim3(DFF / 32, DM / 32), tb, 0, stream>>>(W1, Wt1, DM, DFF);
    transpose_f2b<<<dim3(DM / 32, DFF / 32), tb, 0, stream>>>(W2, Wt2, DFF, DM);

    ln_kernel<<<MROWS, 256, 0, stream>>>(x, gamma1, beta1, h);

    dim3 gg(MROWS / BM, DM / BN);
    gemm_bt<0><<<gg, 256, 0, stream>>>(h, WtQ, bq, Qb, nullptr, nullptr, nullptr, MROWS, DM, DM);
    gemm_bt<0><<<gg, 256, 0, stream>>>(h, WtK, bk, Kb, nullptr, nullptr, nullptr, MROWS, DM, DM);
    gemm_bt<0><<<gg, 256, 0, stream>>>(h, WtV, bv, Vb, nullptr, nullptr, nullptr, MROWS, DM, DM);

    attn_kernel<<<BB * NH * (TT / 4), 256, 0, stream>>>(Qb, Kb, Vb, ctx);

    gemm_bt<1><<<gg, 256, 0, stream>>>(ctx, WtO, bo, x1, x, nullptr, nullptr, MROWS, DM, DM);

    ln_kernel<<<MROWS, 256, 0, stream>>>(x1, gamma2, beta2, h2);

    gemm_bt<2><<<dim3(MROWS / BM, DFF / BN), 256, 0, stream>>>(h2, Wt1, b1, ff, nullptr, nullptr, nullptr, MROWS, DFF, DM);

    gemm_bt<3><<<gg, 256, 0, stream>>>(ff, Wt2, b2, out, x1, x, gate, MROWS, DM, DFF);
}

// Round 4
// 754.553 us; speedup vs baseline: 4.9285x; 4.9285x over previous
//
#include <hip/hip_runtime.h>
#include <hip/hip_bf16.h>
#include <cmath>

typedef unsigned short u16;
typedef __attribute__((ext_vector_type(8))) short short8;
typedef __attribute__((ext_vector_type(4))) float f32x4;

#define DM 1024
#define NH 16
#define DH 64
#define DFF 4096
#define BB 4
#define TT 2048
#define MROWS (BB*TT)

__device__ __forceinline__ float bu2f(u16 u) {
    union { float f; unsigned v; } c; c.v = ((unsigned)u) << 16; return c.f;
}
__device__ __forceinline__ u16 f2bu(float f) {
    __hip_bfloat16 h = __float2bfloat16(f);
    union { __hip_bfloat16 h; u16 u; } c; c.h = h; return c.u;
}

// ---------------- LayerNorm: fp32 in -> bf16 out. One block (256 thr) per row ----------------
__global__ void ln_kernel(const float* __restrict__ x, const float* __restrict__ gamma,
                          const float* __restrict__ beta, u16* __restrict__ out)
{
    int row = blockIdx.x;
    int tid = threadIdx.x;
    float4 v4 = ((const float4*)(x + (size_t)row * DM))[tid];
    float v[4] = { v4.x, v4.y, v4.z, v4.w };
    float s = v[0] + v[1] + v[2] + v[3];
    float ss = v[0]*v[0] + v[1]*v[1] + v[2]*v[2] + v[3]*v[3];
    #pragma unroll
    for (int o = 32; o > 0; o >>= 1) { s += __shfl_down(s, o); ss += __shfl_down(ss, o); }
    __shared__ float red[8];
    int w = tid >> 6;
    if ((tid & 63) == 0) { red[w] = s; red[4 + w] = ss; }
    __syncthreads();
    s  = red[0] + red[1] + red[2] + red[3];
    ss = red[4] + red[5] + red[6] + red[7];
    float mu  = s * (1.0f / DM);
    float var = ss * (1.0f / DM) - mu * mu;
    float rstd = rsqrtf(var + 1e-5f);
    float4 g4 = ((const float4*)gamma)[tid];
    float4 b4 = ((const float4*)beta)[tid];
    float g[4] = { g4.x, g4.y, g4.z, g4.w };
    float b[4] = { b4.x, b4.y, b4.z, b4.w };
    ushort4 o4;
    u16* op = (u16*)&o4;
    #pragma unroll
    for (int i = 0; i < 4; i++) op[i] = f2bu((v[i] - mu) * rstd * g[i] + b[i]);
    ((ushort4*)(out + (size_t)row * DM))[tid] = o4;
}

// ---------------- Transpose + fp32->bf16: in[R][C] fp32 -> out[C][R] bf16 ----------------
__global__ void transpose_f2b(const float* __restrict__ in, u16* __restrict__ out,
                              int R, int C)
{
    __shared__ u16 tile[32][33];
    int bx = blockIdx.x * 32;
    int by = blockIdx.y * 32;
    int tx = threadIdx.x, ty = threadIdx.y;  // 32 x 8
    #pragma unroll
    for (int i = 0; i < 32; i += 8)
        tile[ty + i][tx] = f2bu(in[(size_t)(by + ty + i) * C + bx + tx]);
    __syncthreads();
    #pragma unroll
    for (int i = 0; i < 32; i += 8)
        out[(size_t)(bx + ty + i) * R + by + tx] = tile[tx][ty + i];
}

// ---------------- GEMM: C[M][N] = A[M][K](bf16) * Bt[N][K](bf16)^T + bias(f32) ----------------
#define BM 128
#define BN 128
#define BK 32
#define SA 48

template<int EPI>
__global__ __launch_bounds__(256, 2) void gemm_bt(
    const u16* __restrict__ A, const u16* __restrict__ Bt,
    const float* __restrict__ bias, void* __restrict__ Cv,
    const float* __restrict__ res, const float* __restrict__ x0,
    const float* __restrict__ gate, int M, int N, int K)
{
    __shared__ u16 As[BM * SA];
    __shared__ u16 Bs[BN * SA];
    int tid = threadIdx.x;
    int lane = tid & 63, wave = tid >> 6;
    int wm = (wave & 1) * 64, wn = (wave >> 1) * 64;
    int lm = lane & 15, quad = lane >> 4;
    size_t row0 = (size_t)blockIdx.x * BM;
    size_t col0 = (size_t)blockIdx.y * BN;

    int sr = tid >> 2;
    int sk = (tid & 3) * 8;
    const u16* Ag = A  + (row0 + sr) * (size_t)K + sk;
    const u16* Bg = Bt + (col0 + sr) * (size_t)K + sk;

    f32x4 acc[4][4];
    #pragma unroll
    for (int i = 0; i < 4; i++)
        #pragma unroll
        for (int j = 0; j < 4; j++)
            acc[i][j] = (f32x4){0.f, 0.f, 0.f, 0.f};

    for (int k0 = 0; k0 < K; k0 += BK) {
        uint4 a0 = *(const uint4*)(Ag + k0);
        uint4 a1 = *(const uint4*)(Ag + (size_t)64 * K + k0);
        uint4 b0 = *(const uint4*)(Bg + k0);
        uint4 b1 = *(const uint4*)(Bg + (size_t)64 * K + k0);
        __syncthreads();
        *(uint4*)&As[sr * SA + sk]        = a0;
        *(uint4*)&As[(sr + 64) * SA + sk] = a1;
        *(uint4*)&Bs[sr * SA + sk]        = b0;
        *(uint4*)&Bs[(sr + 64) * SA + sk] = b1;
        __syncthreads();
        short8 af[4], bfr[4];
        #pragma unroll
        for (int t = 0; t < 4; t++) {
            af[t]  = *(const short8*)&As[(wm + t * 16 + lm) * SA + quad * 8];
            bfr[t] = *(const short8*)&Bs[(wn + t * 16 + lm) * SA + quad * 8];
        }
        #pragma unroll
        for (int mt = 0; mt < 4; mt++)
            #pragma unroll
            for (int nt = 0; nt < 4; nt++)
                acc[mt][nt] = __builtin_amdgcn_mfma_f32_16x16x32_bf16(
                    af[mt], bfr[nt], acc[mt][nt], 0, 0, 0);
    }

    u16*   C16 = (u16*)Cv;
    float* Cf  = (float*)Cv;

    #pragma unroll
    for (int mt = 0; mt < 4; mt++) {
        #pragma unroll
        for (int nt = 0; nt < 4; nt++) {
            #pragma unroll
            for (int r = 0; r < 4; r++) {
                size_t row = row0 + wm + mt * 16 + quad * 4 + r;
                size_t col = col0 + wn + nt * 16 + lm;
                size_t idx = row * (size_t)N + col;
                float v = acc[mt][nt][r] + bias[col];
                if (EPI == 0) {
                    C16[idx] = f2bu(v);
                } else if (EPI == 1) {
                    Cf[idx] = v + res[idx];
                } else if (EPI == 2) {
                    v = 0.5f * v * (1.0f + erff(v * 0.70710678118f));
                    C16[idx] = f2bu(v);
                } else {
                    float xv  = x0[idx];
                    float x1v = res[idx];
                    float g   = gate[row >> 11];
                    Cf[idx] = xv + g * (x1v + v - xv);
                }
            }
        }
    }
}

// ---------------- MFMA flash attention ----------------
// 1 block = (b, h, 128 q-rows). 4 waves, each 32 q-rows (2x 16-row MFMA subtiles).
// K/V chunks of 64 keys. QK^T + PV on matrix cores; online softmax in C-layout regs.
__global__ __launch_bounds__(256, 2) void attn_mfma(
    const u16* __restrict__ Q, const u16* __restrict__ Kg,
    const u16* __restrict__ Vg, u16* __restrict__ ctx)
{
    __shared__ u16 Vt[64][72];       // Vt[d][k] = V[kb+k][d]  (stride 72: 16B-aligned, non-pow2)
    __shared__ u16 Pl[4][32][72];    // per-wave P tile [q][k]

    int tid = threadIdx.x, lane = tid & 63, w = tid >> 6;
    int lm = lane & 15, quad = lane >> 4;

    int bi = blockIdx.x;
    int qi = bi & 15, h = (bi >> 4) & 15, b = bi >> 8;
    int q0 = (15 - qi) * 128;        // heavy tiles dispatched first
    int qw = q0 + w * 32;            // this wave's first q row

    const size_t hoff = (size_t)h * DH;
    const u16* Qp = Q  + (size_t)b * TT * DM + hoff;
    const u16* Kp = Kg + (size_t)b * TT * DM + hoff;
    const u16* Vp = Vg + (size_t)b * TT * DM + hoff;

    // Q A-frags, held in registers for the whole kernel.
    short8 aq[2][2];
    #pragma unroll
    for (int qs = 0; qs < 2; qs++)
        #pragma unroll
        for (int dc = 0; dc < 2; dc++)
            aq[qs][dc] = *(const short8*)(Qp + (size_t)(qw + qs*16 + lm) * DM + dc*32 + quad*8);

    f32x4 o[2][4];                   // ctx accumulator, C-layout [qsub][dsub]
    float m_r[2][4], l_r[2][4];      // online-softmax state per q-row (row = quad*4+r)
    #pragma unroll
    for (int qs = 0; qs < 2; qs++) {
        #pragma unroll
        for (int ds = 0; ds < 4; ds++) o[qs][ds] = (f32x4){0.f, 0.f, 0.f, 0.f};
        #pragma unroll
        for (int r = 0; r < 4; r++) { m_r[qs][r] = -INFINITY; l_r[qs][r] = 0.f; }
    }

    const float sc = 0.18033688011f;  // log2(e) / sqrt(64)  -> exp2 domain
    int nch = q0 / 64 + 2;
    for (int c = 0; c < nch; c++) {
        int kb = c * 64;

        // V chunk rows -> registers (before barrier, overlaps)
        uint4 v0 = *(const uint4*)(Vp + (size_t)(kb + lane) * DM + w * 16);
        uint4 v1 = *(const uint4*)(Vp + (size_t)(kb + lane) * DM + w * 16 + 8);
        __syncthreads();              // prior chunk's Vt reads complete
        {
            const u16* p0 = (const u16*)&v0;
            const u16* p1 = (const u16*)&v1;
            #pragma unroll
            for (int i = 0; i < 8; i++) {
                Vt[w * 16 + i][lane]     = p0[i];   // transposed stage
                Vt[w * 16 + 8 + i][lane] = p1[i];
            }
        }
        __syncthreads();              // Vt ready

        // S = Q K^T  (B-frag straight from global; hits L1/L2)
        f32x4 s[2][4];
        #pragma unroll
        for (int qs = 0; qs < 2; qs++)
            #pragma unroll
            for (int ks = 0; ks < 4; ks++)
                s[qs][ks] = (f32x4){0.f, 0.f, 0.f, 0.f};
        #pragma unroll
        for (int ks = 0; ks < 4; ks++) {
            const u16* kr = Kp + (size_t)(kb + ks * 16 + lm) * DM + quad * 8;
            short8 b0 = *(const short8*)(kr);
            short8 b1 = *(const short8*)(kr + 32);
            #pragma unroll
            for (int qs = 0; qs < 2; qs++) {
                s[qs][ks] = __builtin_amdgcn_mfma_f32_16x16x32_bf16(aq[qs][0], b0, s[qs][ks], 0, 0, 0);
                s[qs][ks] = __builtin_amdgcn_mfma_f32_16x16x32_bf16(aq[qs][1], b1, s[qs][ks], 0, 0, 0);
            }
        }

        // scale to exp2 domain + causal mask
        bool maskzone = (kb + 63 > qw);
        #pragma unroll
        for (int qs = 0; qs < 2; qs++)
            #pragma unroll
            for (int ks = 0; ks < 4; ks++)
                #pragma unroll
                for (int r = 0; r < 4; r++) {
                    float v = s[qs][ks][r] * sc;
                    if (maskzone && (kb + ks * 16 + lm > qw + qs * 16 + quad * 4 + r))
                        v = -INFINITY;
                    s[qs][ks][r] = v;
                }

        // online softmax per q-row; write P (bf16) to per-wave LDS tile
        #pragma unroll
        for (int qs = 0; qs < 2; qs++)
            #pragma unroll
            for (int r = 0; r < 4; r++) {
                float cm = fmaxf(fmaxf(s[qs][0][r], s[qs][1][r]),
                                 fmaxf(s[qs][2][r], s[qs][3][r]));
                cm = fmaxf(cm, __shfl_xor(cm, 1));
                cm = fmaxf(cm, __shfl_xor(cm, 2));
                cm = fmaxf(cm, __shfl_xor(cm, 4));
                cm = fmaxf(cm, __shfl_xor(cm, 8));
                float mn = fmaxf(m_r[qs][r], cm);
                float al = exp2f(m_r[qs][r] - mn);
                m_r[qs][r] = mn;
                float ps = 0.f;
                #pragma unroll
                for (int ks = 0; ks < 4; ks++) {
                    float p = exp2f(s[qs][ks][r] - mn);
                    s[qs][ks][r] = p;
                    ps += p;
                }
                ps += __shfl_xor(ps, 1);
                ps += __shfl_xor(ps, 2);
                ps += __shfl_xor(ps, 4);
                ps += __shfl_xor(ps, 8);
                l_r[qs][r] = l_r[qs][r] * al + ps;
                #pragma unroll
                for (int ds = 0; ds < 4; ds++) o[qs][ds][r] *= al;
                #pragma unroll
                for (int ks = 0; ks < 4; ks++)
                    Pl[w][qs * 16 + quad * 4 + r][ks * 16 + lm] = f2bu(s[qs][ks][r]);
            }

        // ctx += P V : A-frag from per-wave Pl, B-frag from shared Vt
        #pragma unroll
        for (int kc = 0; kc < 2; kc++) {
            short8 ap0 = *(const short8*)&Pl[w][lm][kc * 32 + quad * 8];
            short8 ap1 = *(const short8*)&Pl[w][16 + lm][kc * 32 + quad * 8];
            #pragma unroll
            for (int ds = 0; ds < 4; ds++) {
                short8 bv = *(const short8*)&Vt[ds * 16 + lm][kc * 32 + quad * 8];
                o[0][ds] = __builtin_amdgcn_mfma_f32_16x16x32_bf16(ap0, bv, o[0][ds], 0, 0, 0);
                o[1][ds] = __builtin_amdgcn_mfma_f32_16x16x32_bf16(ap1, bv, o[1][ds], 0, 0, 0);
            }
        }
    }

    // epilogue: ctx row = qw + qs*16 + quad*4 + r, col = hoff + ds*16 + lm
    #pragma unroll
    for (int qs = 0; qs < 2; qs++) {
        float inv[4];
        #pragma unroll
        for (int r = 0; r < 4; r++) inv[r] = 1.0f / l_r[qs][r];
        #pragma unroll
        for (int ds = 0; ds < 4; ds++)
            #pragma unroll
            for (int r = 0; r < 4; r++) {
                size_t row = (size_t)(b * TT + qw + qs * 16 + quad * 4 + r);
                ctx[row * DM + hoff + ds * 16 + lm] = f2bu(o[qs][ds][r] * inv[r]);
            }
    }
}

extern "C" void kernel_launch(void* const* d_in, const int* in_sizes, int n_in,
                              void* d_out, int out_size, void* d_ws, size_t ws_size,
                              hipStream_t stream)
{
    const float* x    = (const float*)d_in[0];
    const float* gate = (const float*)d_in[1];
    const float* Wq   = (const float*)d_in[2];
    const float* bq   = (const float*)d_in[3];
    const float* Wk   = (const float*)d_in[4];
    const float* bk   = (const float*)d_in[5];
    const float* Wv   = (const float*)d_in[6];
    const float* bv   = (const float*)d_in[7];
    const float* Wo   = (const float*)d_in[8];
    const float* bo   = (const float*)d_in[9];
    const float* W1   = (const float*)d_in[10];
    const float* b1   = (const float*)d_in[11];
    const float* W2   = (const float*)d_in[12];
    const float* b2   = (const float*)d_in[13];
    const float* gamma1 = (const float*)d_in[14];
    const float* beta1  = (const float*)d_in[15];
    const float* gamma2 = (const float*)d_in[16];
    const float* beta2  = (const float*)d_in[17];
    float* out = (float*)d_out;

    char* ws = (char*)d_ws;
    const size_t MB = 1024 * 1024;
    u16* WtQ = (u16*)(ws + 0 * MB);
    u16* WtK = (u16*)(ws + 2 * MB);
    u16* WtV = (u16*)(ws + 4 * MB);
    u16* WtO = (u16*)(ws + 6 * MB);
    u16* Wt1 = (u16*)(ws + 8 * MB);
    u16* Wt2 = (u16*)(ws + 16 * MB);
    u16* h   = (u16*)(ws + 24 * MB);
    u16* ctx = (u16*)(ws + 24 * MB);
    u16* Qb  = (u16*)(ws + 40 * MB);
    u16* Kb  = (u16*)(ws + 56 * MB);
    u16* Vb  = (u16*)(ws + 72 * MB);
    float* x1 = (float*)(ws + 40 * MB);
    u16* h2  = (u16*)(ws + 72 * MB);
    u16* ff  = (u16*)(ws + 88 * MB);

    dim3 tb(32, 8);
    transpose_f2b<<<dim3(DM / 32, DM / 32), tb, 0, stream>>>(Wq, WtQ, DM, DM);
    transpose_f2b<<<dim3(DM / 32, DM / 32), tb, 0, stream>>>(Wk, WtK, DM, DM);
    transpose_f2b<<<dim3(DM / 32, DM / 32), tb, 0, stream>>>(Wv, WtV, DM, DM);
    transpose_f2b<<<dim3(DM / 32, DM / 32), tb, 0, stream>>>(Wo, WtO, DM, DM);
    transpose_f2b<<<dim3(DFF / 32, DM / 32), tb, 0, stream>>>(W1, Wt1, DM, DFF);
    transpose_f2b<<<dim3(DM / 32, DFF / 32), tb, 0, stream>>>(W2, Wt2, DFF, DM);

    ln_kernel<<<MROWS, 256, 0, stream>>>(x, gamma1, beta1, h);

    dim3 gg(MROWS / BM, DM / BN);
    gemm_bt<0><<<gg, 256, 0, stream>>>(h, WtQ, bq, Qb, nullptr, nullptr, nullptr, MROWS, DM, DM);
    gemm_bt<0><<<gg, 256, 0, stream>>>(h, WtK, bk, Kb, nullptr, nullptr, nullptr, MROWS, DM, DM);
    gemm_bt<0><<<gg, 256, 0, stream>>>(h, WtV, bv, Vb, nullptr, nullptr, nullptr, MROWS, DM, DM);

    attn_mfma<<<BB * NH * (TT / 128), 256, 0, stream>>>(Qb, Kb, Vb, ctx);

    gemm_bt<1><<<gg, 256, 0, stream>>>(ctx, WtO, bo, x1, x, nullptr, nullptr, MROWS, DM, DM);

    ln_kernel<<<MROWS, 256, 0, stream>>>(x1, gamma2, beta2, h2);

    gemm_bt<2><<<dim3(MROWS / BM, DFF / BN), 256, 0, stream>>>(h2, Wt1, b1, ff, nullptr, nullptr, nullptr, MROWS, DFF, DM);

    gemm_bt<3><<<gg, 256, 0, stream>>>(ff, Wt2, b2, out, x1, x, gate, MROWS, DM, DFF);
}